// Round 8
// baseline (144.773 us; speedup 1.0000x reference)
//
#include <hip/hip_runtime.h>

#define B_ 4096
#define C_ 128
#define D_ 768
#define NT 512
#define NW (NT/64)
#define M_MAX 80                    // max class size fast path (8.5 sigma; mean 32, sd 5.6)
#define P_MAX (M_MAX*(M_MAX-1)/2)   // 3160
#define CK 128
#define NCH (D_/CK)                 // 6
#define SROW 132
#define NB_H 1024                   // rank-select histogram buckets
#define SLOTS 2                     // max work items per thread (covers m=80: 861 items)

__device__ __forceinline__ float wave_red(float v){
#pragma unroll
  for (int o = 32; o > 0; o >>= 1) v += __shfl_down(v, o, 64);
  return v;
}
__device__ __forceinline__ float wave_min(float v){
#pragma unroll
  for (int o = 32; o > 0; o >>= 1) v = fminf(v, __shfl_down(v, o, 64));
  return v;
}
__device__ __forceinline__ float wave_max(float v){
#pragma unroll
  for (int o = 32; o > 0; o >>= 1) v = fmaxf(v, __shfl_down(v, o, 64));
  return v;
}
__device__ __forceinline__ float clamp1(float x){ return fminf(fmaxf(x, -1.f), 1.f); }
__device__ __forceinline__ unsigned rotl32(unsigned x, int r){ return (x << r) | (x >> (32 - r)); }
__device__ __forceinline__ float dot4(float4 a, float4 b){
  return fmaf(a.x, b.x, fmaf(a.y, b.y, fmaf(a.z, b.z, a.w * b.w)));
}

// jax.random.uniform(jax.random.key(1),(B,B)) element n: Threefry-2x32 key (0,1),
// counters split in halves. Bit-exact (verified rounds 1-7: absmax 0.0).
__device__ float rand_ij(unsigned n){
  const unsigned half = (unsigned)B_ * (unsigned)B_ / 2u;
  unsigned c0, c1; bool hi;
  if (n < half){ c0 = n; c1 = n + half; hi = false; }
  else         { c0 = n - half; c1 = n; hi = true; }
  const unsigned K0 = 0u, K1 = 1u, K2 = 0x1BD11BDBu;
  unsigned x0 = c0 + K0, x1 = c1 + K1;
#define TFR(r) { x0 += x1; x1 = rotl32(x1, (r)); x1 ^= x0; }
  TFR(13) TFR(15) TFR(26) TFR(6)  x0 += K1; x1 += K2 + 1u;
  TFR(17) TFR(29) TFR(16) TFR(24) x0 += K2; x1 += K0 + 2u;
  TFR(13) TFR(15) TFR(26) TFR(6)  x0 += K0; x1 += K1 + 3u;
  TFR(17) TFR(29) TFR(16) TFR(24) x0 += K1; x1 += K2 + 4u;
  TFR(13) TFR(15) TFR(26) TFR(6)  x0 += K2; x1 += K0 + 5u;
#undef TFR
  unsigned bits = hi ? x1 : x0;
  return __uint_as_float((bits >> 9) | 0x3F800000u) - 1.0f;
}

// p -> (a,b), a<b<m, row-major upper-tri. before(a) = a*(2m-1-a)/2.
__device__ __forceinline__ void decode_pair(int p, int m, int* a_, int* b_){
  float fm = (float)(2*m - 1);
  int a = (int)((fm - sqrtf(fm*fm - 8.0f*(float)p)) * 0.5f);
  a = max(0, min(a, m - 2));
  while (a > 0 && (a*(2*m - 1 - a))/2 > p) --a;
  while (((a + 1)*(2*m - 2 - a))/2 <= p) ++a;
  *a_ = a;
  *b_ = a + 1 + (p - (a*(2*m - 1 - a))/2);
}

// ---- slow-path helpers (unreachable: all classes m<=80; insurance only) ----
__device__ float dotg(const float* x, const float* y){
  float s = 0.f;
  for (int k = 0; k < D_; ++k) s = fmaf(x[k], y[k], s);
  return s;
}
__device__ float S_pair_g(const float* feat, int ga, int gb){
  const float* ra = feat + (size_t)ga * D_;
  const float* rb = feat + (size_t)gb * D_;
  float d = dotg(ra, rb);
  float na = 1.f / fmaxf(sqrtf(dotg(ra, ra)), 1e-12f);
  float nb = 1.f / fmaxf(sqrtf(dotg(rb, rb)), 1e-12f);
  return d * na * nb;
}

// ==== single fused kernel: one block per class, 2x2 register-tiled Gram ====
__global__ __launch_bounds__(NT) void k_all(
    const float* __restrict__ feat, const float* __restrict__ cent,
    const int* __restrict__ labels,
    float* __restrict__ acc2, int* __restrict__ done, float* __restrict__ out)
{
  const int c = blockIdx.x;
  const int tid = threadIdx.x;
  const int wid = tid >> 6, lane = tid & 63;

  __shared__ int   gid_s[M_MAX];
  __shared__ int   mcount;
  __shared__ __align__(16) float tile[M_MAX * SROW];   // 42240 B
  __shared__ __align__(16) float cvec[CK];
  __shared__ __align__(16) float Pd[P_MAX];            // 12640 B
  __shared__ int   hist[NB_H];                         // 4096 B
  __shared__ float selfs[M_MAX];    // raw self-dot -> rnorm in place
  __shared__ float ecs[M_MAX];      // raw EC dot -> scaled in place
  __shared__ float cn_sh;
  __shared__ float mnb[NW], mxb[NW];
  __shared__ float lo_sh, sF_sh;
  __shared__ int   B0_sh;
  __shared__ float thr_sh;
  __shared__ float redbuf[16];

  // ---- phase A: collect members (order-independent math) + zero hist ----
  if (tid == 0) mcount = 0;
  __syncthreads();
  for (int i = tid; i < B_; i += NT){
    if (labels[i] == c){
      int p = atomicAdd(&mcount, 1);
      if (p < M_MAX) gid_s[p] = i;
    }
  }
  for (int i = tid; i < NB_H; i += NT) hist[i] = 0;
  __syncthreads();
  const int m = mcount;

  float lloss = 0.f, lw = 0.f;

  if (m >= 2 && m <= M_MAX){
    const int P = m * (m - 1) / 2;
    const int k0 = (P - 1) >> 1;
    const float wc = (float)m;
    const int G2 = (m + 1) >> 1;
    const int mpad = G2 << 1;
    const int T2 = G2 * (G2 + 1) / 2;       // 2x2 gram tiles, ta<=tb
    const int NIDX = T2 + G2 + 1;           // + EC tiles + center self

    // slot setup: sA/sB = row bases; -1 = cvec; -2 = inactive
    int sA[SLOTS], sB[SLOTS];
    float ac[SLOTS][4];
#pragma unroll
    for (int s = 0; s < SLOTS; ++s){
      sA[s] = -2; sB[s] = -2;
      ac[s][0] = ac[s][1] = ac[s][2] = ac[s][3] = 0.f;
      int idx = tid + s * NT;
      if (idx < NIDX){
        if (idx < T2){
          int a, b; decode_pair(idx, G2 + 1, &a, &b);   // pairs-with-diag trick
          sA[s] = 2 * a; sB[s] = 2 * (b - 1);
        } else if (idx < T2 + G2){ sA[s] = 2 * (idx - T2); sB[s] = -1; }
        else { sA[s] = -1; sB[s] = -1; }
      }
    }

    // ---- phase B: chunked staging + tiled Gram (accs persist across chunks) ----
    for (int ch = 0; ch < NCH; ++ch){
      const int d0 = ch * CK;
      __syncthreads();
      for (int e = tid; e < mpad * (CK/4); e += NT){
        int r = e >> 5, j = e & 31;
        float4 v = make_float4(0.f, 0.f, 0.f, 0.f);
        if (r < m) v = ((const float4*)(feat + (size_t)gid_s[r] * D_ + d0))[j];
        ((float4*)&tile[r * SROW])[j] = v;
      }
      if (tid < CK/4)
        ((float4*)cvec)[tid] = ((const float4*)(cent + (size_t)c * D_ + d0))[tid];
      __syncthreads();
#pragma unroll
      for (int s = 0; s < SLOTS; ++s){
        if (sA[s] == -2) continue;
        const float4* A0 = (sA[s] >= 0) ? (const float4*)&tile[sA[s] * SROW]       : (const float4*)cvec;
        const float4* A1 = (sA[s] >= 0) ? (const float4*)&tile[(sA[s] + 1) * SROW] : (const float4*)cvec;
        const float4* B0 = (sB[s] >= 0) ? (const float4*)&tile[sB[s] * SROW]       : (const float4*)cvec;
        const float4* B1 = (sB[s] >= 0) ? (const float4*)&tile[(sB[s] + 1) * SROW] : (const float4*)cvec;
        float c0 = 0.f, c1 = 0.f, c2 = 0.f, c3 = 0.f;
#pragma unroll 8
        for (int j = 0; j < CK/4; ++j){
          float4 a0 = A0[j], a1 = A1[j], b0 = B0[j], b1 = B1[j];
          c0 += dot4(a0, b0); c1 += dot4(a0, b1);
          c2 += dot4(a1, b0); c3 += dot4(a1, b1);
        }
        ac[s][0] += c0; ac[s][1] += c1; ac[s][2] += c2; ac[s][3] += c3;
      }
    }
    __syncthreads();

    // owners write raw selfs / ecs / center-self
#pragma unroll
    for (int s = 0; s < SLOTS; ++s){
      if (sA[s] == -2) continue;
      if (sB[s] >= 0){
        if (sA[s] == sB[s]){                       // diagonal gram tile
          if (sA[s] < m)     selfs[sA[s]]     = ac[s][0];
          if (sA[s] + 1 < m) selfs[sA[s] + 1] = ac[s][3];
        }
      } else if (sA[s] >= 0){                      // EC tile
        if (sA[s] < m)     ecs[sA[s]]     = ac[s][0];
        if (sA[s] + 1 < m) ecs[sA[s] + 1] = ac[s][2];
      } else cn_sh = ac[s][0];                     // center self-dot
    }
    __syncthreads();
    if (tid < m){
      float rn  = 1.f / fmaxf(sqrtf(selfs[tid]), 1e-12f);
      float cno = 1.f / fmaxf(sqrtf(cn_sh), 1e-12f);
      selfs[tid] = rn;
      ecs[tid] = ecs[tid] * rn * cno;
    }
    __syncthreads();

    // ---- phase C: normalize in regs, write Pd, track min/max ----
    float pmn = 1e30f, pmx = -1e30f;
#pragma unroll
    for (int s = 0; s < SLOTS; ++s){
      if (sB[s] < 0) continue;                     // gram tiles only
      const int ta2 = sA[s], tb2 = sB[s];
#pragma unroll
      for (int k = 0; k < 4; ++k){
        int a = ta2 + (k >> 1), b = tb2 + (k & 1);
        if (a < b && b < m){
          float S = ac[s][k] * selfs[a] * selfs[b];
          ac[s][k] = S;
          float pd = 1.f - clamp1(S);
          int p = ((a * (2*m - 1 - a)) >> 1) + b - a - 1;
          Pd[p] = pd;
          pmn = fminf(pmn, pd); pmx = fmaxf(pmx, pd);
        }
      }
    }
    pmn = wave_min(pmn); pmx = wave_max(pmx);
    if (lane == 0){ mnb[wid] = pmn; mxb[wid] = pmx; }
    __syncthreads();
    if (tid == 0){
      float mn = mnb[0], mx = mxb[0];
#pragma unroll
      for (int i = 1; i < NW; ++i){ mn = fminf(mn, mnb[i]); mx = fmaxf(mx, mxb[i]); }
      lo_sh = mn;
      sF_sh = (float)NB_H / fmaxf(mx - mn, 1e-20f);
    }
    __syncthreads();
    const float lo = lo_sh, sF = sF_sh;

    // ---- phase D: LDS-atomic histogram + single-wave scan ----
#pragma unroll
    for (int s = 0; s < SLOTS; ++s){
      if (sB[s] < 0) continue;
      const int ta2 = sA[s], tb2 = sB[s];
#pragma unroll
      for (int k = 0; k < 4; ++k){
        int a = ta2 + (k >> 1), b = tb2 + (k & 1);
        if (a < b && b < m){
          float pd = 1.f - clamp1(ac[s][k]);
          int bkt = (int)((pd - lo) * sF);
          bkt = max(0, min(NB_H - 1, bkt));
          atomicAdd(&hist[bkt], 1);
        }
      }
    }
    __syncthreads();
    if (tid < 64){
      const int G = NB_H / 64;                     // 16 buckets per lane
      int loc[NB_H / 64];
      int ssum = 0;
      const int base = tid * G;
#pragma unroll
      for (int k = 0; k < G; ++k){ loc[k] = hist[base + k]; ssum += loc[k]; }
      int inc = ssum;
#pragma unroll
      for (int o = 1; o < 64; o <<= 1){
        int v = __shfl_up(inc, o, 64);
        if (tid >= o) inc += v;
      }
      int excl = inc - ssum;
      if (excl <= k0 && k0 < inc){
        int accq = excl;
#pragma unroll
        for (int k = 0; k < G; ++k){
          if (accq + loc[k] > k0){ B0_sh = base + k; break; }
          accq += loc[k];
        }
      }
    }
    __syncthreads();
    const int bsel = B0_sh;

    // exact recount, candidates in selected bucket only (bit-exact threshold)
    {
      const float4* Pd4 = (const float4*)Pd;
      const int nq4 = P >> 2;
#pragma unroll
      for (int s = 0; s < SLOTS; ++s){
        if (sB[s] < 0) continue;
        const int ta2 = sA[s], tb2 = sB[s];
#pragma unroll
        for (int k = 0; k < 4; ++k){
          int a = ta2 + (k >> 1), b = tb2 + (k & 1);
          if (a < b && b < m){
            float pdp = 1.f - clamp1(ac[s][k]);
            int bkt = (int)((pdp - lo) * sF);
            bkt = max(0, min(NB_H - 1, bkt));
            if (bkt == bsel){
              int lt = 0, eq = 0;
#pragma unroll 4
              for (int q4 = 0; q4 < nq4; ++q4){
                float4 v = Pd4[q4];
                lt += (v.x < pdp) + (v.y < pdp) + (v.z < pdp) + (v.w < pdp);
                eq += (v.x == pdp) + (v.y == pdp) + (v.z == pdp) + (v.w == pdp);
              }
              for (int q = nq4 << 2; q < P; ++q){
                float pdq = Pd[q];
                lt += (pdq < pdp); eq += (pdq == pdp);
              }
              if (lt <= k0 && k0 < lt + eq) thr_sh = pdp;
            }
          }
        }
      }
    }
    __syncthreads();
    const float thr = thr_sh;

    // ---- phase E: loss over selected pairs (all reg-resident) ----
#pragma unroll
    for (int s = 0; s < SLOTS; ++s){
      if (sB[s] < 0) continue;
      const int ta2 = sA[s], tb2 = sB[s];
#pragma unroll
      for (int k = 0; k < 4; ++k){
        int a = ta2 + (k >> 1), b = tb2 + (k & 1);
        if (a < b && b < m){
          float S = ac[s][k];
          float pd = 1.f - clamp1(S);
          if (pd > thr){
            int ga = gid_s[a], gb = gid_s[b];
            float ea = ecs[a], eb = ecs[b];
            int i, j; float eci, ecj;
            if (ga < gb){ i = ga; j = gb; eci = ea; ecj = eb; }
            else        { i = gb; j = ga; eci = eb; ecj = ea; }
            float r = rand_ij((unsigned)i * (unsigned)B_ + (unsigned)j);
            float omr = 1.f - r;
            float n2 = r * r + omr * omr + 2.f * r * omr * S;   // raw S
            float nrm = fmaxf(sqrtf(fmaxf(n2, 0.f)), 1e-12f);
            float dt = clamp1((r * eci + omr * ecj) / nrm);
            lloss += wc * (1.f - dt);
            lw += wc;
          }
        }
      }
    }
  } else if (m > M_MAX){
    // correctness-only fallback (impossible here: max m ~47, verified R1-R7)
    int* mem = (int*)tile;                         // 4096 <= M_MAX*SROW
    if (tid == 0) B0_sh = 0;
    __syncthreads();
    for (int i = tid; i < B_; i += NT)
      if (labels[i] == c){ int p = atomicAdd(&B0_sh, 1); mem[p] = i; }
    __syncthreads();
    const int P = m * (m - 1) / 2;
    const int k0 = (P - 1) >> 1;
    const float wc = (float)m;
    const float* cc = cent + (size_t)c * D_;
    const float cno = 1.f / fmaxf(sqrtf(dotg(cc, cc)), 1e-12f);
    for (int p = tid; p < P; p += NT){
      int a, b; decode_pair(p, m, &a, &b);
      float pdp = 1.f - clamp1(S_pair_g(feat, mem[a], mem[b]));
      int lt = 0, eq = 0;
      for (int q = 0; q < P; ++q){
        int a2, b2; decode_pair(q, m, &a2, &b2);
        float pdq = 1.f - clamp1(S_pair_g(feat, mem[a2], mem[b2]));
        lt += (pdq < pdp); eq += (pdq == pdp);
      }
      if (lt <= k0 && k0 < lt + eq) thr_sh = pdp;
    }
    __syncthreads();
    const float thr = thr_sh;
    for (int p = tid; p < P; p += NT){
      int a, b; decode_pair(p, m, &a, &b);
      int ga = mem[a], gb = mem[b];
      float S = S_pair_g(feat, ga, gb);
      float pd = 1.f - clamp1(S);
      if (pd > thr){
        if (ga > gb){ int t2 = ga; ga = gb; gb = t2; }
        const float* ra = feat + (size_t)ga * D_;
        const float* rb = feat + (size_t)gb * D_;
        float eci = dotg(ra, cc) / fmaxf(sqrtf(dotg(ra, ra)), 1e-12f) * cno;
        float ecj = dotg(rb, cc) / fmaxf(sqrtf(dotg(rb, rb)), 1e-12f) * cno;
        float r = rand_ij((unsigned)ga * (unsigned)B_ + (unsigned)gb);
        float omr = 1.f - r;
        float n2 = r * r + omr * omr + 2.f * r * omr * S;
        float nrm = fmaxf(sqrtf(fmaxf(n2, 0.f)), 1e-12f);
        float dt = clamp1((r * eci + omr * ecj) / nrm);
        lloss += wc * (1.f - dt);
        lw += wc;
      }
    }
  }
  // m < 2: nothing to add

  // ---- phase F: block reduce + device accumulate + last-block finalize ----
  lloss = wave_red(lloss); lw = wave_red(lw);
  if (lane == 0){ redbuf[wid] = lloss; redbuf[8 + wid] = lw; }
  __syncthreads();
  if (tid == 0){
    float tl = 0.f, tw = 0.f;
#pragma unroll
    for (int i = 0; i < NW; ++i){ tl += redbuf[i]; tw += redbuf[8 + i]; }
    if (tl != 0.f || tw != 0.f){
      atomicAdd(&acc2[0], tl);
      atomicAdd(&acc2[1], tw);
    }
    __threadfence();
    int old = atomicAdd(done, 1);
    if (old == C_ - 1){
      float l = atomicAdd(&acc2[0], 0.f);
      float w = atomicAdd(&acc2[1], 0.f);
      out[0] = (w > 0.f) ? (l / w) : 0.f;
    }
  }
}

extern "C" void kernel_launch(void* const* d_in, const int* in_sizes, int n_in,
                              void* d_out, int out_size, void* d_ws, size_t ws_size,
                              hipStream_t stream)
{
  const float* feat   = (const float*)d_in[0];
  const float* cent   = (const float*)d_in[1];
  const int*   labels = (const int*)d_in[2];
  // d_in[3] = cam_ids: unused by the reference computation.

  char* ws = (char*)d_ws;
  float* acc2 = (float*)(ws + 0);   // loss, wsum
  int*   done = (int*)(ws + 8);

  hipMemsetAsync(ws, 0, 16, stream);
  k_all<<<C_, NT, 0, stream>>>(feat, cent, labels, acc2, done, (float*)d_out);
}